// Round 2
// baseline (1099.429 us; speedup 1.0000x reference)
//
#include <hip/hip_runtime.h>
#include <hip/hip_bf16.h>

// Problem constants
// B=4, S=2048, S_ENC=1024, HIDDEN=2048, H=16, KVH=4, D=128
// Q GEMM:  [8192 x 2048] = [8192 x 2048] @ [2048 x 2048]
// K GEMM:  [4096 x  512] = [4096 x 2048] @ [2048 x  512]
// V GEMM:  same as K, output transposed to Vt[b][kvh][d][s]
// attn:    per (b,h): softmax(Q K^T / sqrt(128)) V   (in place over Q)
// out:     [8192 x 2048] = attn @ Wo

typedef short  bf16x8 __attribute__((ext_vector_type(8)));
typedef float  f32x4  __attribute__((ext_vector_type(4)));

__device__ __forceinline__ unsigned short f2bf(float f) {
    union { float f; unsigned u; } v; v.f = f;
    unsigned r = v.u + 0x7fffu + ((v.u >> 16) & 1u);  // RNE
    return (unsigned short)(r >> 16);
}
__device__ __forceinline__ float bf2f(unsigned short u) {
    union { unsigned u; float f; } v; v.u = ((unsigned)u) << 16;
    return v.f;
}

// ---------------------------------------------------------------------------
// GEMM: C[M,N] = A[M,K] @ B[K,N].  A fp32 (AKIND=0) or bf16 (AKIND=1),
// B always fp32 (weights), converted to bf16 in LDS.
// EPI: 0 = bf16 row-major, 1 = bf16 transposed V layout, 2 = fp32 row-major
// Tile 128x128x32, 256 threads (4 waves, 2x2), mfma_f32_16x16x32_bf16.
// All dims divide tile sizes exactly for this problem (no bounds checks).
// ---------------------------------------------------------------------------
template <int AKIND, int EPI>
__launch_bounds__(256)
__global__ void gemm_kernel(const void* __restrict__ Av,
                            const float* __restrict__ B,
                            void* __restrict__ Out,
                            int M, int N, int K) {
    __shared__ __align__(16) unsigned short As[128 * 40];  // [row][k] pad->40
    __shared__ __align__(16) unsigned short Bs[128 * 40];  // [n][k]  (B^T) pad->40

    const int tid  = threadIdx.x;
    const int bx   = blockIdx.x;   // N tile
    const int by   = blockIdx.y;   // M tile
    const int row0 = by * 128;
    const int n0   = bx * 128;

    const int lane = tid & 63;
    const int wv   = tid >> 6;
    const int wr   = (wv >> 1) * 64;
    const int wc   = (wv & 1) * 64;
    const int la   = lane & 15;
    const int lb   = (lane >> 4) * 8;

    f32x4 acc[4][4] = {};

    for (int k0 = 0; k0 < K; k0 += 32) {
        // ---- stage A tile [128 x 32] -> bf16 LDS ----
        if (AKIND == 0) {
            const float* A = (const float*)Av;
            #pragma unroll
            for (int r = 0; r < 4; ++r) {
                int idx = tid + r * 256;       // 0..1023
                int row = idx >> 3;
                int c4  = (idx & 7) << 2;
                const float4 v = *(const float4*)(A + (size_t)(row0 + row) * K + k0 + c4);
                ushort4 h;
                h.x = f2bf(v.x); h.y = f2bf(v.y); h.z = f2bf(v.z); h.w = f2bf(v.w);
                *(ushort4*)&As[row * 40 + c4] = h;
            }
        } else {
            const unsigned short* A = (const unsigned short*)Av;
            #pragma unroll
            for (int r = 0; r < 2; ++r) {
                int idx = tid + r * 256;       // 0..511
                int row = idx >> 2;
                int c8  = (idx & 3) << 3;
                uint4 v = *(const uint4*)(A + (size_t)(row0 + row) * K + k0 + c8);
                *(uint4*)&As[row * 40 + c8] = v;
            }
        }
        // ---- stage B tile [32 x 128] transposed -> Bs[n][k] ----
        #pragma unroll
        for (int r = 0; r < 4; ++r) {
            int idx = tid + r * 256;           // 0..1023
            int kr  = idx >> 5;                // 0..31
            int n4  = (idx & 31) << 2;         // 0..124
            const float4 v = *(const float4*)(B + (size_t)(k0 + kr) * N + n0 + n4);
            Bs[(n4 + 0) * 40 + kr] = f2bf(v.x);
            Bs[(n4 + 1) * 40 + kr] = f2bf(v.y);
            Bs[(n4 + 2) * 40 + kr] = f2bf(v.z);
            Bs[(n4 + 3) * 40 + kr] = f2bf(v.w);
        }
        __syncthreads();

        bf16x8 a[4], b[4];
        #pragma unroll
        for (int i = 0; i < 4; ++i)
            a[i] = *(const bf16x8*)&As[(wr + i * 16 + la) * 40 + lb];
        #pragma unroll
        for (int j = 0; j < 4; ++j)
            b[j] = *(const bf16x8*)&Bs[(wc + j * 16 + la) * 40 + lb];
        #pragma unroll
        for (int i = 0; i < 4; ++i)
            #pragma unroll
            for (int j = 0; j < 4; ++j)
                acc[i][j] = __builtin_amdgcn_mfma_f32_16x16x32_bf16(a[i], b[j], acc[i][j], 0, 0, 0);
        __syncthreads();
    }

    // ---- epilogue ----
    const int lg = lane >> 4;
    #pragma unroll
    for (int i = 0; i < 4; ++i) {
        #pragma unroll
        for (int j = 0; j < 4; ++j) {
            #pragma unroll
            for (int r = 0; r < 4; ++r) {
                int row_g = row0 + wr + i * 16 + lg * 4 + r;
                int col_g = n0 + wc + j * 16 + la;
                float val = acc[i][j][r];
                if (EPI == 0) {
                    ((unsigned short*)Out)[(size_t)row_g * N + col_g] = f2bf(val);
                } else if (EPI == 1) {
                    // row_g = b*1024 + s ; col_g = kvh*128 + d
                    int b_  = row_g >> 10, s_ = row_g & 1023;
                    int kvh = col_g >> 7,  d_ = col_g & 127;
                    ((unsigned short*)Out)[(((size_t)(b_ * 4 + kvh) * 128 + d_) << 10) + s_] = f2bf(val);
                } else {
                    ((float*)Out)[(size_t)row_g * N + col_g] = val;
                }
            }
        }
    }
}

// ---------------------------------------------------------------------------
// In-place RMS norm over contiguous 128-element segments (one wave each).
// ---------------------------------------------------------------------------
__launch_bounds__(256)
__global__ void rmsnorm_kernel(unsigned short* __restrict__ x,
                               const float* __restrict__ w, int nseg) {
    int seg  = blockIdx.x * 4 + (threadIdx.x >> 6);
    if (seg >= nseg) return;
    int lane = threadIdx.x & 63;
    size_t base = (size_t)seg * 128 + lane * 2;
    unsigned v = *(const unsigned*)&x[base];
    float x0 = bf2f((unsigned short)(v & 0xffff));
    float x1 = bf2f((unsigned short)(v >> 16));
    float s = x0 * x0 + x1 * x1;
    #pragma unroll
    for (int m = 1; m < 64; m <<= 1) s += __shfl_xor(s, m, 64);
    float rinv = rsqrtf(s * (1.0f / 128.0f) + 1e-6f);
    x0 = x0 * rinv * w[lane * 2];
    x1 = x1 * rinv * w[lane * 2 + 1];
    unsigned o = (unsigned)f2bf(x0) | ((unsigned)f2bf(x1) << 16);
    *(unsigned*)&x[base] = o;
}

// ---------------------------------------------------------------------------
// Flash attention (non-causal, GQA 4:1), IN PLACE over Q.
// Grid: 1024 blocks = (b,h) x 16 q-tiles.  Block: 256 thr = 4 waves,
// each wave owns 32 q-rows.  KV iterated in tiles of 64.
// Q/O: bf16 [B*S][H*D]; K: bf16 [B*S_enc][KVH*D]; Vt: bf16 [B][KVH][D][S_enc]
// Each block reads only its own (b,h,qt) Q region (into registers, at kernel
// start) and writes only that same region at the end -> O may alias Q.
// ---------------------------------------------------------------------------
__launch_bounds__(256)
__global__ void attn_kernel(const unsigned short* __restrict__ Q,
                            const unsigned short* __restrict__ Kb,
                            const unsigned short* __restrict__ Vt,
                            unsigned short* __restrict__ Ob) {
    __shared__ __align__(16) unsigned short Klds[64 * 136];   // [key][d] pad->136
    __shared__ __align__(16) unsigned short Vtlds[128 * 72];  // [d][key] pad->72
    __shared__ __align__(16) unsigned short Plds[4][32 * 72]; // per-wave [q][key] pad->72

    const int tid  = threadIdx.x;
    const int bid  = blockIdx.x;
    const int qt   = bid & 15;
    const int bh   = bid >> 4;     // 0..63
    const int b    = bh >> 4;
    const int h    = bh & 15;
    const int kvh  = h >> 2;

    const int lane = tid & 63;
    const int wv   = tid >> 6;
    const int la   = lane & 15;
    const int lg   = lane >> 4;
    const int lb   = lg * 8;
    const float scale = 0.08838834764831845f;  // 1/sqrt(128)

    const int qr0 = qt * 128 + wv * 32;

    // Q fragments held in registers for the whole kernel
    bf16x8 aq[2][4];
    #pragma unroll
    for (int i = 0; i < 2; ++i)
        #pragma unroll
        for (int t = 0; t < 4; ++t)
            aq[i][t] = *(const bf16x8*)&Q[(size_t)(b * 2048 + qr0 + i * 16 + la) * 2048
                                          + h * 128 + t * 32 + lb];

    f32x4 oacc[2][8] = {};
    float m_run[2][4], l_part[2][4];
    #pragma unroll
    for (int i = 0; i < 2; ++i)
        #pragma unroll
        for (int r = 0; r < 4; ++r) { m_run[i][r] = -INFINITY; l_part[i][r] = 0.0f; }

    const unsigned short* Kbase  = Kb + (size_t)(b * 1024) * 512 + kvh * 128;
    const unsigned short* Vtbase = Vt + (size_t)(b * 4 + kvh) * 128 * 1024;

    for (int kt = 0; kt < 16; ++kt) {
        // ---- stage K tile [64 keys x 128 d] ----
        #pragma unroll
        for (int r = 0; r < 4; ++r) {
            int idx  = tid + r * 256;     // 0..1023
            int srow = idx >> 4;
            int c8   = (idx & 15) << 3;
            uint4 v = *(const uint4*)(Kbase + (size_t)(kt * 64 + srow) * 512 + c8);
            *(uint4*)&Klds[srow * 136 + c8] = v;
        }
        // ---- stage Vt tile [128 d x 64 keys] ----  (FIXED: r<4, full 128 rows)
        #pragma unroll
        for (int r = 0; r < 4; ++r) {
            int idx  = tid + r * 256;     // 0..1023
            int drow = idx >> 3;          // 0..127
            int c8   = (idx & 7) << 3;    // 0..56
            uint4 v = *(const uint4*)(Vtbase + (size_t)drow * 1024 + kt * 64 + c8);
            *(uint4*)&Vtlds[drow * 72 + c8] = v;
        }
        __syncthreads();

        // ---- S = Q K^T ----
        f32x4 sacc[2][4] = {};
        #pragma unroll
        for (int j = 0; j < 4; ++j) {
            bf16x8 bk[4];
            #pragma unroll
            for (int t = 0; t < 4; ++t)
                bk[t] = *(const bf16x8*)&Klds[(j * 16 + la) * 136 + t * 32 + lb];
            #pragma unroll
            for (int t = 0; t < 4; ++t)
                #pragma unroll
                for (int i = 0; i < 2; ++i)
                    sacc[i][j] = __builtin_amdgcn_mfma_f32_16x16x32_bf16(aq[i][t], bk[t], sacc[i][j], 0, 0, 0);
        }
        #pragma unroll
        for (int i = 0; i < 2; ++i)
            #pragma unroll
            for (int j = 0; j < 4; ++j)
                sacc[i][j] *= scale;

        // ---- online softmax (per q-row; rows live in (lg, reg)) ----
        #pragma unroll
        for (int i = 0; i < 2; ++i) {
            #pragma unroll
            for (int r = 0; r < 4; ++r) {
                float mt = fmaxf(fmaxf(sacc[i][0][r], sacc[i][1][r]),
                                 fmaxf(sacc[i][2][r], sacc[i][3][r]));
                mt = fmaxf(mt, __shfl_xor(mt, 1, 64));
                mt = fmaxf(mt, __shfl_xor(mt, 2, 64));
                mt = fmaxf(mt, __shfl_xor(mt, 4, 64));
                mt = fmaxf(mt, __shfl_xor(mt, 8, 64));
                float mo = m_run[i][r];
                float mn = fmaxf(mo, mt);
                float alpha = __expf(mo - mn);
                m_run[i][r] = mn;
                float ls = 0.0f;
                #pragma unroll
                for (int j = 0; j < 4; ++j) {
                    float p = __expf(sacc[i][j][r] - mn);
                    sacc[i][j][r] = p;
                    ls += p;
                }
                l_part[i][r] = l_part[i][r] * alpha + ls;
                #pragma unroll
                for (int df = 0; df < 8; ++df) oacc[i][df][r] *= alpha;
            }
        }

        // ---- P -> LDS (bf16), re-read in MFMA-A layout ----
        #pragma unroll
        for (int i = 0; i < 2; ++i)
            #pragma unroll
            for (int j = 0; j < 4; ++j)
                #pragma unroll
                for (int r = 0; r < 4; ++r)
                    Plds[wv][(i * 16 + lg * 4 + r) * 72 + j * 16 + la] = f2bf(sacc[i][j][r]);
        __syncthreads();

        // ---- O += P V ----
        #pragma unroll
        for (int ks = 0; ks < 2; ++ks) {
            bf16x8 pa[2];
            #pragma unroll
            for (int i = 0; i < 2; ++i)
                pa[i] = *(const bf16x8*)&Plds[wv][(i * 16 + la) * 72 + ks * 32 + lb];
            #pragma unroll
            for (int df = 0; df < 8; ++df) {
                bf16x8 bv = *(const bf16x8*)&Vtlds[(df * 16 + la) * 72 + ks * 32 + lb];
                #pragma unroll
                for (int i = 0; i < 2; ++i)
                    oacc[i][df] = __builtin_amdgcn_mfma_f32_16x16x32_bf16(pa[i], bv, oacc[i][df], 0, 0, 0);
            }
        }
        __syncthreads();
    }

    // ---- finalize: divide by l, write bf16 ----
    #pragma unroll
    for (int i = 0; i < 2; ++i) {
        #pragma unroll
        for (int r = 0; r < 4; ++r) {
            float l = l_part[i][r];
            l += __shfl_xor(l, 1, 64);
            l += __shfl_xor(l, 2, 64);
            l += __shfl_xor(l, 4, 64);
            l += __shfl_xor(l, 8, 64);
            float inv = 1.0f / l;
            int row_g = b * 2048 + qr0 + i * 16 + lg * 4 + r;
            #pragma unroll
            for (int df = 0; df < 8; ++df) {
                int col_g = h * 128 + df * 16 + la;
                Ob[(size_t)row_g * 2048 + col_g] = f2bf(oacc[i][df][r] * inv);
            }
        }
    }
}

// ---------------------------------------------------------------------------
extern "C" void kernel_launch(void* const* d_in, const int* in_sizes, int n_in,
                              void* d_out, int out_size, void* d_ws, size_t ws_size,
                              hipStream_t stream) {
    const float* hidden = (const float*)d_in[0];  // [4,2048,2048]
    const float* enc    = (const float*)d_in[1];  // [4,1024,2048]
    const float* Wq     = (const float*)d_in[2];  // [2048,2048]
    const float* Wk     = (const float*)d_in[3];  // [2048,512]
    const float* Wv     = (const float*)d_in[4];  // [2048,512]
    const float* Wo     = (const float*)d_in[5];  // [2048,2048]
    const float* qw     = (const float*)d_in[6];  // [128]
    const float* kw     = (const float*)d_in[7];  // [128]
    float* out = (float*)d_out;

    unsigned short* Qu = (unsigned short*)d_ws;            // 8192*2048 bf16 (Q, then attn out in place)
    unsigned short* Kn = Qu + (size_t)8192 * 2048;         // 4096*512 bf16
    unsigned short* Vt = Kn + (size_t)4096 * 512;          // 4*4*128*1024 bf16
    // total ws: 41,943,040 bytes (40 MB)

    dim3 blk(256);
    // Q = hidden @ Wq   (bf16 row-major, unnormalized)
    gemm_kernel<0, 0><<<dim3(16, 64), blk, 0, stream>>>(hidden, Wq, Qu, 8192, 2048, 2048);
    // K = enc @ Wk      (bf16 row-major, unnormalized)
    gemm_kernel<0, 0><<<dim3(4, 32), blk, 0, stream>>>(enc, Wk, Kn, 4096, 512, 2048);
    // Vt = (enc @ Wv)^T per (b,kvh)
    gemm_kernel<0, 1><<<dim3(4, 32), blk, 0, stream>>>(enc, Wv, Vt, 4096, 512, 2048);
    // RMS norms (in place)
    rmsnorm_kernel<<<dim3(32768), blk, 0, stream>>>(Qu, qw, 8192 * 16);
    rmsnorm_kernel<<<dim3(4096), blk, 0, stream>>>(Kn, kw, 4096 * 4);
    // attention (in place: O over Q)
    attn_kernel<<<dim3(1024), blk, 0, stream>>>(Qu, Kn, Vt, Qu);
    // out = attn @ Wo   (fp32)
    gemm_kernel<1, 2><<<dim3(16, 64), blk, 0, stream>>>(Qu, Wo, out, 8192, 2048, 2048);
}

// Round 3
// 544.448 us; speedup vs baseline: 2.0193x; 2.0193x over previous
//
#include <hip/hip_runtime.h>
#include <hip/hip_bf16.h>

// B=4, S=2048, S_ENC=1024, HIDDEN=2048, H=16, KVH=4, D=128
// Pipeline:
//   cvt:   enc fp32 -> bf16
//   tpose: Wq,Wk,Wv,Wo fp32 [K][N] -> bf16 [N][K]
//   gemm2<1,0>: Q  = hidden @ Wq  (A fp32 reg-staged, B global_load_lds)
//   gemm2<0,0>: K  = enc_bf @ Wk
//   gemm2<0,1>: Vt = (enc_bf @ Wv)^T  per (b,kvh)
//   rmsnorm Q, K
//   attn (in place over Q)
//   gemm2<0,2>: out = attn @ Wo (fp32)

typedef short  bf16x8 __attribute__((ext_vector_type(8)));
typedef float  f32x4  __attribute__((ext_vector_type(4)));
typedef unsigned short us;

__device__ __forceinline__ us f2bf(float f) {
    union { float f; unsigned u; } v; v.f = f;
    unsigned r = v.u + 0x7fffu + ((v.u >> 16) & 1u);  // RNE
    return (us)(r >> 16);
}
__device__ __forceinline__ float bf2f(us u) {
    union { unsigned u; float f; } v; v.u = ((unsigned)u) << 16;
    return v.f;
}

typedef __attribute__((address_space(3))) unsigned int lds_u32;
typedef __attribute__((address_space(1))) const unsigned int glb_u32;

__device__ __forceinline__ void gl_lds16(const us* g, us* l) {
    __builtin_amdgcn_global_load_lds((glb_u32*)g, (lds_u32*)l, 16, 0, 0);
}

// ---------------------------------------------------------------------------
// fp32 -> bf16 convert, 8 elems/thread, exact grids only
// ---------------------------------------------------------------------------
__launch_bounds__(256)
__global__ void cvt_kernel(const float* __restrict__ in, us* __restrict__ out) {
    size_t i = ((size_t)blockIdx.x * 256 + threadIdx.x) * 8;
    float4 v0 = *(const float4*)(in + i);
    float4 v1 = *(const float4*)(in + i + 4);
    bf16x8 h;
    h[0] = f2bf(v0.x); h[1] = f2bf(v0.y); h[2] = f2bf(v0.z); h[3] = f2bf(v0.w);
    h[4] = f2bf(v1.x); h[5] = f2bf(v1.y); h[6] = f2bf(v1.z); h[7] = f2bf(v1.w);
    *(bf16x8*)(out + i) = h;
}

// ---------------------------------------------------------------------------
// transpose + convert: out[N][K] bf16 = in[K][N] fp32.  64x64 tiles.
// grid (N/64, K/64), 256 threads.
// ---------------------------------------------------------------------------
__launch_bounds__(256)
__global__ void tpose_kernel(const float* __restrict__ in, us* __restrict__ out,
                             int K, int N) {
    __shared__ us tile[64][65];
    const int n0 = blockIdx.x * 64;
    const int k0 = blockIdx.y * 64;
    const int t  = threadIdx.x;
    const int r  = t >> 4;          // 0..15
    const int c4 = (t & 15) * 4;    // 0..60
    #pragma unroll
    for (int rr = 0; rr < 64; rr += 16) {
        float4 v = *(const float4*)(in + (size_t)(k0 + r + rr) * N + n0 + c4);
        tile[r + rr][c4 + 0] = f2bf(v.x);
        tile[r + rr][c4 + 1] = f2bf(v.y);
        tile[r + rr][c4 + 2] = f2bf(v.z);
        tile[r + rr][c4 + 3] = f2bf(v.w);
    }
    __syncthreads();
    #pragma unroll
    for (int rr = 0; rr < 64; rr += 16) {
        ushort4 o;
        o.x = tile[c4 + 0][r + rr];
        o.y = tile[c4 + 1][r + rr];
        o.z = tile[c4 + 2][r + rr];
        o.w = tile[c4 + 3][r + rr];
        *(ushort4*)(out + (size_t)(n0 + r + rr) * K + k0 + c4) = o;
    }
}

// ---------------------------------------------------------------------------
// m97-structure GEMM: C[M,N] = A[M,K] @ Bt[N,K]^T
// AFP32: 1 = A fp32 (reg-staged + cvt), 0 = A bf16 (global_load_lds)
// EPI:   0 = bf16 row-major, 1 = bf16 Vt layout, 2 = fp32 row-major
// 128x128 tile, BK=64, 256 thr (4 waves 2x2), linear LDS, 2 barriers/K-step.
// ---------------------------------------------------------------------------
template <int AFP32, int EPI>
__launch_bounds__(256)
__global__ void gemm2_kernel(const void* __restrict__ Av,
                             const us* __restrict__ Bt,
                             void* __restrict__ Out,
                             int M, int N, int K) {
    __shared__ __align__(16) us As[128 * 64];
    __shared__ __align__(16) us Bs[128 * 64];

    const int tid  = threadIdx.x;
    const int lane = tid & 63;
    const int wv   = tid >> 6;
    const int row0 = blockIdx.y * 128;
    const int n0   = blockIdx.x * 128;
    const int wr   = (wv >> 1) * 64;
    const int wc   = (wv & 1) * 64;
    const int la   = lane & 15;
    const int lg   = lane >> 4;
    const int lb   = lg * 8;

    const int srow = lane >> 3;       // 0..7 (per-lane global row within 8-row group)
    const int scol = (lane & 7) * 8;  // 0..56 shorts

    const float* Af = (const float*)Av;
    const us*    Ab = (const us*)Av;

    f32x4 acc[4][4] = {};

    for (int k0 = 0; k0 < K; k0 += 64) {
        // ---- B stage: 4 x global_load_lds per wave (async) ----
        #pragma unroll
        for (int r = 0; r < 4; ++r) {
            int brow = wv * 32 + r * 8;
            gl_lds16(Bt + (size_t)(n0 + brow + srow) * K + k0 + scol, &Bs[brow * 64]);
        }
        // ---- A stage ----
        if (AFP32) {
            #pragma unroll
            for (int seg = 0; seg < 4; ++seg) {
                int row = seg * 32 + (tid >> 3);
                int col = (tid & 7) * 8;
                const float* src = Af + (size_t)(row0 + row) * K + k0 + col;
                float4 v0 = *(const float4*)src;
                float4 v1 = *(const float4*)(src + 4);
                bf16x8 h;
                h[0] = f2bf(v0.x); h[1] = f2bf(v0.y); h[2] = f2bf(v0.z); h[3] = f2bf(v0.w);
                h[4] = f2bf(v1.x); h[5] = f2bf(v1.y); h[6] = f2bf(v1.z); h[7] = f2bf(v1.w);
                *(bf16x8*)&As[row * 64 + col] = h;
            }
        } else {
            #pragma unroll
            for (int r = 0; r < 4; ++r) {
                int arow = wv * 32 + r * 8;
                gl_lds16(Ab + (size_t)(row0 + arow + srow) * K + k0 + scol, &As[arow * 64]);
            }
        }
        __syncthreads();

        // ---- fragments + 32 MFMA ----
        bf16x8 af[2][4], bg[2][4];
        #pragma unroll
        for (int kk = 0; kk < 2; ++kk) {
            #pragma unroll
            for (int i = 0; i < 4; ++i)
                af[kk][i] = *(const bf16x8*)&As[(wr + i * 16 + la) * 64 + kk * 32 + lb];
            #pragma unroll
            for (int j = 0; j < 4; ++j)
                bg[kk][j] = *(const bf16x8*)&Bs[(wc + j * 16 + la) * 64 + kk * 32 + lb];
        }
        #pragma unroll
        for (int kk = 0; kk < 2; ++kk)
            #pragma unroll
            for (int i = 0; i < 4; ++i)
                #pragma unroll
                for (int j = 0; j < 4; ++j)
                    acc[i][j] = __builtin_amdgcn_mfma_f32_16x16x32_bf16(af[kk][i], bg[kk][j], acc[i][j], 0, 0, 0);
        __syncthreads();
    }

    // ---- epilogue ----
    #pragma unroll
    for (int i = 0; i < 4; ++i) {
        #pragma unroll
        for (int j = 0; j < 4; ++j) {
            #pragma unroll
            for (int r = 0; r < 4; ++r) {
                int row_g = row0 + wr + i * 16 + lg * 4 + r;
                int col_g = n0 + wc + j * 16 + la;
                float val = acc[i][j][r];
                if (EPI == 0) {
                    ((us*)Out)[(size_t)row_g * N + col_g] = f2bf(val);
                } else if (EPI == 1) {
                    int b_  = row_g >> 10, s_ = row_g & 1023;
                    int kvh = col_g >> 7,  d_ = col_g & 127;
                    ((us*)Out)[(((size_t)(b_ * 4 + kvh) * 128 + d_) << 10) + s_] = f2bf(val);
                } else {
                    ((float*)Out)[(size_t)row_g * N + col_g] = val;
                }
            }
        }
    }
}

// ---------------------------------------------------------------------------
// In-place RMS norm over contiguous 128-element segments (one wave each).
// ---------------------------------------------------------------------------
__launch_bounds__(256)
__global__ void rmsnorm_kernel(us* __restrict__ x, const float* __restrict__ w, int nseg) {
    int seg  = blockIdx.x * 4 + (threadIdx.x >> 6);
    if (seg >= nseg) return;
    int lane = threadIdx.x & 63;
    size_t base = (size_t)seg * 128 + lane * 2;
    unsigned v = *(const unsigned*)&x[base];
    float x0 = bf2f((us)(v & 0xffff));
    float x1 = bf2f((us)(v >> 16));
    float s = x0 * x0 + x1 * x1;
    #pragma unroll
    for (int m = 1; m < 64; m <<= 1) s += __shfl_xor(s, m, 64);
    float rinv = rsqrtf(s * (1.0f / 128.0f) + 1e-6f);
    x0 = x0 * rinv * w[lane * 2];
    x1 = x1 * rinv * w[lane * 2 + 1];
    unsigned o = (unsigned)f2bf(x0) | ((unsigned)f2bf(x1) << 16);
    *(unsigned*)&x[base] = o;
}

// ---------------------------------------------------------------------------
// Flash attention (non-causal, GQA 4:1), IN PLACE over Q.
// Grid 1024 = (b,h) x 16 q-tiles.  256 thr = 4 waves x 32 q-rows.  KV tiles 64.
// ---------------------------------------------------------------------------
__launch_bounds__(256)
__global__ void attn_kernel(const us* __restrict__ Q,
                            const us* __restrict__ Kb,
                            const us* __restrict__ Vt,
                            us* __restrict__ Ob) {
    __shared__ __align__(16) us Klds[64 * 136];
    __shared__ __align__(16) us Vtlds[128 * 72];
    __shared__ __align__(16) us Plds[4][32 * 72];

    const int tid  = threadIdx.x;
    const int bid  = blockIdx.x;
    const int qt   = bid & 15;
    const int bh   = bid >> 4;
    const int b    = bh >> 4;
    const int h    = bh & 15;
    const int kvh  = h >> 2;

    const int lane = tid & 63;
    const int wv   = tid >> 6;
    const int la   = lane & 15;
    const int lg   = lane >> 4;
    const int lb   = lg * 8;
    const float scale = 0.08838834764831845f;

    const int qr0 = qt * 128 + wv * 32;

    bf16x8 aq[2][4];
    #pragma unroll
    for (int i = 0; i < 2; ++i)
        #pragma unroll
        for (int t = 0; t < 4; ++t)
            aq[i][t] = *(const bf16x8*)&Q[(size_t)(b * 2048 + qr0 + i * 16 + la) * 2048
                                          + h * 128 + t * 32 + lb];

    f32x4 oacc[2][8] = {};
    float m_run[2][4], l_part[2][4];
    #pragma unroll
    for (int i = 0; i < 2; ++i)
        #pragma unroll
        for (int r = 0; r < 4; ++r) { m_run[i][r] = -INFINITY; l_part[i][r] = 0.0f; }

    const us* Kbase  = Kb + (size_t)(b * 1024) * 512 + kvh * 128;
    const us* Vtbase = Vt + (size_t)(b * 4 + kvh) * 128 * 1024;

    for (int kt = 0; kt < 16; ++kt) {
        #pragma unroll
        for (int r = 0; r < 4; ++r) {
            int idx  = tid + r * 256;
            int srow = idx >> 4;
            int c8   = (idx & 15) << 3;
            uint4 v = *(const uint4*)(Kbase + (size_t)(kt * 64 + srow) * 512 + c8);
            *(uint4*)&Klds[srow * 136 + c8] = v;
        }
        #pragma unroll
        for (int r = 0; r < 4; ++r) {
            int idx  = tid + r * 256;
            int drow = idx >> 3;
            int c8   = (idx & 7) << 3;
            uint4 v = *(const uint4*)(Vtbase + (size_t)drow * 1024 + kt * 64 + c8);
            *(uint4*)&Vtlds[drow * 72 + c8] = v;
        }
        __syncthreads();

        f32x4 sacc[2][4] = {};
        #pragma unroll
        for (int j = 0; j < 4; ++j) {
            bf16x8 bk[4];
            #pragma unroll
            for (int t = 0; t < 4; ++t)
                bk[t] = *(const bf16x8*)&Klds[(j * 16 + la) * 136 + t * 32 + lb];
            #pragma unroll
            for (int t = 0; t < 4; ++t)
                #pragma unroll
                for (int i = 0; i < 2; ++i)
                    sacc[i][j] = __builtin_amdgcn_mfma_f32_16x16x32_bf16(aq[i][t], bk[t], sacc[i][j], 0, 0, 0);
        }
        #pragma unroll
        for (int i = 0; i < 2; ++i)
            #pragma unroll
            for (int j = 0; j < 4; ++j)
                sacc[i][j] *= scale;

        #pragma unroll
        for (int i = 0; i < 2; ++i) {
            #pragma unroll
            for (int r = 0; r < 4; ++r) {
                float mt = fmaxf(fmaxf(sacc[i][0][r], sacc[i][1][r]),
                                 fmaxf(sacc[i][2][r], sacc[i][3][r]));
                mt = fmaxf(mt, __shfl_xor(mt, 1, 64));
                mt = fmaxf(mt, __shfl_xor(mt, 2, 64));
                mt = fmaxf(mt, __shfl_xor(mt, 4, 64));
                mt = fmaxf(mt, __shfl_xor(mt, 8, 64));
                float mo = m_run[i][r];
                float mn = fmaxf(mo, mt);
                float alpha = __expf(mo - mn);
                m_run[i][r] = mn;
                float ls = 0.0f;
                #pragma unroll
                for (int j = 0; j < 4; ++j) {
                    float p = __expf(sacc[i][j][r] - mn);
                    sacc[i][j][r] = p;
                    ls += p;
                }
                l_part[i][r] = l_part[i][r] * alpha + ls;
                #pragma unroll
                for (int df = 0; df < 8; ++df) oacc[i][df][r] *= alpha;
            }
        }

        #pragma unroll
        for (int i = 0; i < 2; ++i)
            #pragma unroll
            for (int j = 0; j < 4; ++j)
                #pragma unroll
                for (int r = 0; r < 4; ++r)
                    Plds[wv][(i * 16 + lg * 4 + r) * 72 + j * 16 + la] = f2bf(sacc[i][j][r]);
        __syncthreads();

        #pragma unroll
        for (int ks = 0; ks < 2; ++ks) {
            bf16x8 pa[2];
            #pragma unroll
            for (int i = 0; i < 2; ++i)
                pa[i] = *(const bf16x8*)&Plds[wv][(i * 16 + la) * 72 + ks * 32 + lb];
            #pragma unroll
            for (int df = 0; df < 8; ++df) {
                bf16x8 bv = *(const bf16x8*)&Vtlds[(df * 16 + la) * 72 + ks * 32 + lb];
                #pragma unroll
                for (int i = 0; i < 2; ++i)
                    oacc[i][df] = __builtin_amdgcn_mfma_f32_16x16x32_bf16(pa[i], bv, oacc[i][df], 0, 0, 0);
            }
        }
        __syncthreads();
    }

    #pragma unroll
    for (int i = 0; i < 2; ++i) {
        #pragma unroll
        for (int r = 0; r < 4; ++r) {
            float l = l_part[i][r];
            l += __shfl_xor(l, 1, 64);
            l += __shfl_xor(l, 2, 64);
            l += __shfl_xor(l, 4, 64);
            l += __shfl_xor(l, 8, 64);
            float inv = 1.0f / l;
            int row_g = b * 2048 + qr0 + i * 16 + lg * 4 + r;
            #pragma unroll
            for (int df = 0; df < 8; ++df) {
                int col_g = h * 128 + df * 16 + la;
                Ob[(size_t)row_g * 2048 + col_g] = f2bf(oacc[i][df][r] * inv);
            }
        }
    }
}

// ---------------------------------------------------------------------------
extern "C" void kernel_launch(void* const* d_in, const int* in_sizes, int n_in,
                              void* d_out, int out_size, void* d_ws, size_t ws_size,
                              hipStream_t stream) {
    const float* hidden = (const float*)d_in[0];  // [8192,2048]
    const float* enc    = (const float*)d_in[1];  // [4096,2048]
    const float* Wq     = (const float*)d_in[2];  // [2048,2048]
    const float* Wk     = (const float*)d_in[3];  // [2048,512]
    const float* Wv     = (const float*)d_in[4];  // [2048,512]
    const float* Wo     = (const float*)d_in[5];  // [2048,2048]
    const float* qw     = (const float*)d_in[6];
    const float* kw     = (const float*)d_in[7];
    float* out = (float*)d_out;

    // workspace layout (bf16 elements); total 68 MB
    us* enc_bf = (us*)d_ws;                       //  8,388,608
    us* WqT    = enc_bf + (size_t)8388608;        //  4,194,304
    us* WkT    = WqT    + (size_t)4194304;        //  1,048,576
    us* WvT    = WkT    + (size_t)1048576;        //  1,048,576
    us* WoT    = WvT    + (size_t)1048576;        //  4,194,304
    us* Qu     = WoT    + (size_t)4194304;        // 16,777,216 (Q, then attn out in place)
    // Kn/Vt alias WqT (dead after Q GEMM; stream order guarantees safety)
    us* Kn     = WqT;                             //  2,097,152
    us* Vt     = WqT + (size_t)2097152;           //  2,097,152

    dim3 blk(256);
    // convert / transpose prep
    cvt_kernel<<<dim3(4096), blk, 0, stream>>>(enc, enc_bf);                       // 4096*2048
    tpose_kernel<<<dim3(32, 32), blk, 0, stream>>>(Wq, WqT, 2048, 2048);
    tpose_kernel<<<dim3(8, 32),  blk, 0, stream>>>(Wk, WkT, 2048, 512);
    tpose_kernel<<<dim3(8, 32),  blk, 0, stream>>>(Wv, WvT, 2048, 512);
    tpose_kernel<<<dim3(32, 32), blk, 0, stream>>>(Wo, WoT, 2048, 2048);

    // Q = hidden @ Wq  (A fp32 reg-staged)
    gemm2_kernel<1, 0><<<dim3(16, 64), blk, 0, stream>>>(hidden, WqT, Qu, 8192, 2048, 2048);
    // K = enc @ Wk ; Vt = (enc @ Wv)^T
    gemm2_kernel<0, 0><<<dim3(4, 32), blk, 0, stream>>>(enc_bf, WkT, Kn, 4096, 512, 2048);
    gemm2_kernel<0, 1><<<dim3(4, 32), blk, 0, stream>>>(enc_bf, WvT, Vt, 4096, 512, 2048);
    // norms
    rmsnorm_kernel<<<dim3(32768), blk, 0, stream>>>(Qu, qw, 8192 * 16);
    rmsnorm_kernel<<<dim3(4096),  blk, 0, stream>>>(Kn, kw, 4096 * 4);
    // attention (in place)
    attn_kernel<<<dim3(1024), blk, 0, stream>>>(Qu, Kn, Vt, Qu);
    // out = attn @ Wo (fp32)
    gemm2_kernel<0, 2><<<dim3(16, 64), blk, 0, stream>>>(Qu, WoT, out, 8192, 2048, 2048);
}